// Round 6
// baseline (97.443 us; speedup 1.0000x reference)
//
#include <hip/hip_runtime.h>
#include <hip/hip_bf16.h>

#define N_NODES 4096
#define D_MODEL 256
#define NWORDS 128   // bitmap words per row (4096/32)
#define MAXC 512     // max neighbors per row (avg ~33)

typedef __attribute__((ext_vector_type(8))) short short8;
typedef __attribute__((ext_vector_type(4))) short short4v;
typedef __attribute__((ext_vector_type(4))) float f32x4;

__device__ __forceinline__ unsigned short f2b(float f) {  // fp32 -> bf16 RTN
    unsigned u = __float_as_uint(f);
    return (unsigned short)((u + 0x7FFFu + ((u >> 16) & 1u)) >> 16);
}
__device__ __forceinline__ float b2f(unsigned short u) {
    return __uint_as_float((unsigned)u << 16);
}

// ---------------- prep: convw (blocks 0..2047) | zero bitmap (2048..2559)
// ---------------- | detect (2560) -----------------------------------------
__global__ __launch_bounds__(256) void prep_kernel(const float* __restrict__ Wq,
        const float* __restrict__ Wk, const float* __restrict__ Wv,
        const float* __restrict__ Wo, const float* __restrict__ Wm1,
        const float* __restrict__ Wm2, unsigned short* __restrict__ wbf,
        uint4* __restrict__ bitmap, const int* __restrict__ ei,
        int* __restrict__ flag) {
    int b = blockIdx.x;
    if (b < 2048) {                       // weight fp32 [K][M] -> bf16 [M][K]
        int e = b * 256 + threadIdx.x;    // 0..524287
        const float* W; int base, K, M;
        if (e < 262144) {
            int r = e >> 16;
            W = (r == 0) ? Wq : (r == 1) ? Wk : (r == 2) ? Wv : Wo;
            base = r << 16; K = 256; M = 256;
        } else if (e < 393216) { W = Wm1; base = 262144; K = 256; M = 512; }
        else                   { W = Wm2; base = 393216; K = 512; M = 256; }
        int i = e - base;
        int m = i / K, k = i - m * K;
        wbf[e] = f2b(W[k * M + m]);
    } else if (b < 2560) {                // zero the 2MB bitmap
        bitmap[(size_t)(b - 2048) * 256 + threadIdx.x] = uint4{0, 0, 0, 0};
    } else if (threadIdx.x == 0) {        // edge dtype detect
        int is64 = 1;
        for (int i = 1; i < 128; i += 2)
            if (ei[i] != 0) { is64 = 0; break; }
        *flag = is64;
    }
}

// ---------------- build dedup'd adjacency bitmap --------------------------
__global__ __launch_bounds__(256) void build_adj(const int* __restrict__ ei, int E,
                                                 const int* __restrict__ flag,
                                                 unsigned* __restrict__ bitmap) {
    int e = blockIdx.x * blockDim.x + threadIdx.x;
    if (e >= E) return;
    int n, m;
    if (*flag) { n = ei[2 * e]; m = ei[2 * (E + e)]; }
    else       { n = ei[e];     m = ei[E + e]; }
    atomicOr(&bitmap[n * NWORDS + (m >> 5)], 1u << (m & 31));
}

// ---------------- bf16 MFMA GEMM, resident A panel, optional fused LN -----
// C[4096 x M] = op(A) @ B. BT: [M][K] bf16 (B pre-transposed).
// LNF: A_f32 [4096][256] f32, LN'd into LDS. else A bf16 [4096][K].
// 64x64 tile, 4 waves of 32x32.
// MODE 1: +bias,GELU -> bf16 | 2: +bias+R -> f32 | 3: qkv 3-part bias -> bf16
template <int K, int MODE, bool LNF>
__global__ __launch_bounds__(256) void gemm_bf16(const unsigned short* __restrict__ A,
        const float* __restrict__ Af, const float* __restrict__ lng,
        const float* __restrict__ lnb, const unsigned short* __restrict__ BT,
        const float* __restrict__ bias, const float* __restrict__ bias_k,
        const float* __restrict__ bias_v, const float* __restrict__ R,
        float* __restrict__ Cf, unsigned short* __restrict__ Cb, int M) {
    __shared__ unsigned short Asm[64][K + 8];   // stride ≡ 4 dwords mod 32
    __shared__ unsigned short Bsm[64][72];
    int tid = threadIdx.x;
    int brow = blockIdx.x * 64, bcol = blockIdx.y * 64;
    int wid = tid >> 6, lane = tid & 63;
    int wr = wid >> 1, wc = wid & 1;
    int l15 = lane & 15, lhi = lane >> 4;

    if (LNF) {   // LayerNorm 64 rows of Af into Asm (wave per row, 16 rows/wave)
        float4 gv = *(const float4*)&lng[lane * 4];
        float4 bv = *(const float4*)&lnb[lane * 4];
        for (int r = wid; r < 64; r += 4) {
            float4 xv = *(const float4*)&Af[(size_t)(brow + r) * 256 + lane * 4];
            float s  = xv.x + xv.y + xv.z + xv.w;
            float s2 = xv.x * xv.x + xv.y * xv.y + xv.z * xv.z + xv.w * xv.w;
            #pragma unroll
            for (int off = 32; off; off >>= 1) {
                s  += __shfl_down(s, off, 64);
                s2 += __shfl_down(s2, off, 64);
            }
            s = __shfl(s, 0, 64); s2 = __shfl(s2, 0, 64);
            float mu  = s * (1.0f / 256.0f);
            float var = s2 * (1.0f / 256.0f) - mu * mu;
            float inv = rsqrtf(var + 1e-5f);
            short4v o;
            o.x = (short)f2b((xv.x - mu) * inv * gv.x + bv.x);
            o.y = (short)f2b((xv.y - mu) * inv * gv.y + bv.y);
            o.z = (short)f2b((xv.z - mu) * inv * gv.z + bv.z);
            o.w = (short)f2b((xv.w - mu) * inv * gv.w + bv.w);
            *(short4v*)&Asm[r][lane * 4] = o;
        }
    } else {     // stage bf16 A panel, coalesced
        #pragma unroll
        for (int i = 0; i < (64 * K / 8) / 256; ++i) {
            int fl = (tid + i * 256) * 8;
            int r = fl / K, cc = fl % K;
            *(short8*)&Asm[r][cc] = *(const short8*)&A[(size_t)(brow + r) * K + cc];
        }
    }

    int r0 = tid >> 3, c0 = (tid & 7) << 3;
    const unsigned short* Bp0 = BT + (size_t)(bcol + r0) * K + c0;
    const unsigned short* Bp1 = BT + (size_t)(bcol + r0 + 32) * K + c0;
    f32x4 acc[2][2] = {};
    for (int k0 = 0; k0 < K; k0 += 64) {
        short8 b0v = *(const short8*)(Bp0 + k0);
        short8 b1v = *(const short8*)(Bp1 + k0);
        __syncthreads();                    // Asm ready (1st iter) / Bsm free
        *(short8*)&Bsm[r0][c0] = b0v;
        *(short8*)&Bsm[r0 + 32][c0] = b1v;
        __syncthreads();
        #pragma unroll
        for (int ks = 0; ks < 2; ++ks) {
            int ka = k0 + ks * 32 + lhi * 8;
            int kb = ks * 32 + lhi * 8;
            short8 a_0 = *(const short8*)&Asm[wr * 32 + l15][ka];
            short8 a_1 = *(const short8*)&Asm[wr * 32 + 16 + l15][ka];
            short8 b_0 = *(const short8*)&Bsm[wc * 32 + l15][kb];
            short8 b_1 = *(const short8*)&Bsm[wc * 32 + 16 + l15][kb];
            acc[0][0] = __builtin_amdgcn_mfma_f32_16x16x32_bf16(a_0, b_0, acc[0][0], 0, 0, 0);
            acc[0][1] = __builtin_amdgcn_mfma_f32_16x16x32_bf16(a_0, b_1, acc[0][1], 0, 0, 0);
            acc[1][0] = __builtin_amdgcn_mfma_f32_16x16x32_bf16(a_1, b_0, acc[1][0], 0, 0, 0);
            acc[1][1] = __builtin_amdgcn_mfma_f32_16x16x32_bf16(a_1, b_1, acc[1][1], 0, 0, 0);
        }
    }
    #pragma unroll
    for (int sm = 0; sm < 2; ++sm)
        #pragma unroll
        for (int sn = 0; sn < 2; ++sn) {
            int col = bcol + wc * 32 + sn * 16 + l15;
            float bs;
            if (MODE == 3)
                bs = (col < 256) ? bias[col]
                   : (col < 512) ? bias_k[col - 256] : bias_v[col - 512];
            else
                bs = bias[col];
            #pragma unroll
            for (int r = 0; r < 4; ++r) {
                int row = brow + wr * 32 + sm * 16 + lhi * 4 + r;
                float c = acc[sm][sn][r] + bs;
                if (MODE == 1) {
                    c = 0.5f * c * (1.0f + erff(c * 0.70710678118654752f));
                    Cb[(size_t)row * M + col] = f2b(c);
                } else if (MODE == 2) {
                    Cf[(size_t)row * M + col] = c + R[(size_t)row * M + col];
                } else {
                    Cb[(size_t)row * M + col] = f2b(c);
                }
            }
        }
}

// ---------------- sparse attention w/ inline bitmap->index scan -----------
// qkv: [N][768] bf16 (q|k|v). 1 block/row, 8 head-groups of 32 lanes.
__global__ __launch_bounds__(256) void attn_kernel(const unsigned short* __restrict__ qkv,
        const unsigned* __restrict__ bitmap, unsigned short* __restrict__ y) {
    int n = blockIdx.x, tid = threadIdx.x;
    int h = tid >> 5, lane = tid & 31;
    __shared__ int sIdx[MAXC];
    __shared__ int wsum[2];
    __shared__ int scnt;

    // q load first: global latency hides under the bitmap scan
    const unsigned short* qp = qkv + (size_t)n * 768 + h * 32;
    float qreg[32];
    #pragma unroll
    for (int i = 0; i < 4; ++i) {
        short8 q8 = *(const short8*)(qp + i * 8);
        #pragma unroll
        for (int j = 0; j < 8; ++j) qreg[i * 8 + j] = b2f((unsigned short)q8[j]);
    }

    unsigned word = 0; int pc = 0, pre = 0;
    if (tid < 128) {                       // popc prefix scan of 128 words
        word = bitmap[n * NWORDS + tid];
        pc = __popc(word);
        pre = pc;
        #pragma unroll
        for (int off = 1; off < 64; off <<= 1) {
            int u = __shfl_up(pre, off, 64);
            if ((tid & 63) >= off) pre += u;
        }
        if ((tid & 63) == 63) wsum[tid >> 6] = pre;
    }
    __syncthreads();
    if (tid < 128) {
        int base = (tid >= 64) ? wsum[0] : 0;
        int off = base + pre - pc;
        while (word) {
            int bit = __ffs(word) - 1;
            word &= word - 1;
            if (off < MAXC) sIdx[off] = (tid << 5) + bit;
            ++off;
        }
        if (tid == 127) scnt = min(base + pre, MAXC);
    }
    __syncthreads();
    int c = scnt;

    const float sc = 0.17677669529663687f;   // 1/sqrt(32)
    float m_run = -INFINITY, S = 0.0f, acc = 0.0f;
    for (int b0 = 0; b0 < c; b0 += 32) {
        int j = b0 + lane;
        float s = -INFINITY;
        if (j < c) {
            const unsigned short* kp = qkv + (size_t)sIdx[j] * 768 + 256 + h * 32;
            float d = 0.0f;
            #pragma unroll
            for (int i = 0; i < 4; ++i) {
                short8 k8 = *(const short8*)(kp + i * 8);
                #pragma unroll
                for (int e = 0; e < 8; ++e)
                    d = fmaf(qreg[i * 8 + e], b2f((unsigned short)k8[e]), d);
            }
            s = d * sc;
        }
        float bm = s;
        #pragma unroll
        for (int off = 16; off; off >>= 1) bm = fmaxf(bm, __shfl_xor(bm, off, 32));
        float newM = fmaxf(m_run, bm);
        float p = (j < c) ? __expf(s - newM) : 0.0f;
        float bs = p;
        #pragma unroll
        for (int off = 16; off; off >>= 1) bs += __shfl_xor(bs, off, 32);
        float scale = __expf(m_run - newM);
        S = S * scale + bs;
        acc *= scale;
        int lim = min(32, c - b0);
        const unsigned short* vbase = qkv + 512 + h * 32 + lane;
        #pragma unroll 4
        for (int jj = 0; jj < lim; ++jj) {
            float pj = __shfl(p, jj, 32);
            int m = sIdx[b0 + jj];
            acc = fmaf(pj, b2f(vbase[(size_t)m * 768]), acc);
        }
        m_run = newM;
    }
    y[(size_t)n * 256 + h * 32 + lane] = f2b(acc / S);
}

extern "C" void kernel_launch(void* const* d_in, const int* in_sizes, int n_in,
                              void* d_out, int out_size, void* d_ws, size_t ws_size,
                              hipStream_t stream) {
    const float* x   = (const float*)d_in[0];
    const int*   ei  = (const int*)d_in[1];
    const float* Wq  = (const float*)d_in[2];  const float* bq  = (const float*)d_in[3];
    const float* Wk  = (const float*)d_in[4];  const float* bk  = (const float*)d_in[5];
    const float* Wv  = (const float*)d_in[6];  const float* bv  = (const float*)d_in[7];
    const float* Wo  = (const float*)d_in[8];  const float* bo  = (const float*)d_in[9];
    const float* g1  = (const float*)d_in[10]; const float* b1  = (const float*)d_in[11];
    const float* g2  = (const float*)d_in[12]; const float* b2  = (const float*)d_in[13];
    const float* Wm1 = (const float*)d_in[14]; const float* bm1 = (const float*)d_in[15];
    const float* Wm2 = (const float*)d_in[16]; const float* bm2 = (const float*)d_in[17];
    float* out = (float*)d_out;
    int E = in_sizes[1] / 2;   // 135168

    char* WS = (char*)d_ws;
    const size_t MB = 1u << 20;
    unsigned*       bitmap = (unsigned*)WS;                     // [0,2MB)
    int*            flag   = (int*)(WS + 2 * MB);               // 4B
    unsigned short* wbf    = (unsigned short*)(WS + 3 * MB);    // 1MB
    unsigned short* y      = (unsigned short*)(WS + 4 * MB);    // 2MB
    float*          x1     = (float*)(WS + 6 * MB);             // 4MB
    unsigned short* m1     = (unsigned short*)(WS + 10 * MB);   // 4MB
    unsigned short* qkv    = (unsigned short*)(WS + 16 * MB);   // 6MB

    const unsigned short* WTqkv = wbf;            // q|k|v stacked along M
    const unsigned short* WTo   = wbf + 196608;
    const unsigned short* WTm1  = wbf + 262144;
    const unsigned short* WTm2  = wbf + 393216;

    prep_kernel<<<2561, 256, 0, stream>>>(Wq, Wk, Wv, Wo, Wm1, Wm2, wbf,
                                          (uint4*)bitmap, ei, flag);
    build_adj<<<(E + 255) / 256, 256, 0, stream>>>(ei, E, flag, bitmap);

    dim3 gqkv(N_NODES / 64, 12), g256(N_NODES / 64, 4), g512(N_NODES / 64, 8);
    // qkv = LN1(x) @ Wqkv + b   (LN fused)
    gemm_bf16<256, 3, true><<<gqkv, 256, 0, stream>>>(nullptr, x, g1, b1, WTqkv,
            bq, bk, bv, nullptr, nullptr, qkv, 768);

    attn_kernel<<<N_NODES, 256, 0, stream>>>(qkv, bitmap, y);

    // x1 = x + y @ Wo + bo
    gemm_bf16<256, 2, false><<<g256, 256, 0, stream>>>(y, nullptr, nullptr, nullptr,
            WTo, bo, nullptr, nullptr, x, x1, nullptr, 256);
    // m1 = gelu(LN2(x1) @ Wm1 + bm1)   (LN fused)
    gemm_bf16<256, 1, true><<<g512, 256, 0, stream>>>(nullptr, x1, g2, b2, WTm1,
            bm1, nullptr, nullptr, nullptr, nullptr, m1, 512);
    // out = x1 + m1 @ Wm2 + bm2
    gemm_bf16<512, 2, false><<<g256, 256, 0, stream>>>(m1, nullptr, nullptr, nullptr,
            WTm2, bm2, nullptr, nullptr, x1, out, nullptr, 256);
}

// Round 7
// 88.786 us; speedup vs baseline: 1.0975x; 1.0975x over previous
//
#include <hip/hip_runtime.h>
#include <hip/hip_bf16.h>

#define N_NODES 4096
#define D_MODEL 256
#define NWORDS 128   // bitmap words per row (4096/32)
#define MAXC 512     // max neighbors per row (avg ~33)

typedef __attribute__((ext_vector_type(8))) short short8;
typedef __attribute__((ext_vector_type(4))) float f32x4;

__device__ __forceinline__ unsigned short f2b(float f) {  // fp32 -> bf16 RTN
    unsigned u = __float_as_uint(f);
    return (unsigned short)((u + 0x7FFFu + ((u >> 16) & 1u)) >> 16);
}
__device__ __forceinline__ float b2f(unsigned short u) {
    return __uint_as_float((unsigned)u << 16);
}

// ---------------- prep: convw (blocks 0..2047) | zero bitmap (2048..2559)
// ---------------- | detect (2560) -----------------------------------------
__global__ __launch_bounds__(256) void prep_kernel(const float* __restrict__ Wq,
        const float* __restrict__ Wk, const float* __restrict__ Wv,
        const float* __restrict__ Wo, const float* __restrict__ Wm1,
        const float* __restrict__ Wm2, unsigned short* __restrict__ wbf,
        uint4* __restrict__ bitmap, const int* __restrict__ ei,
        int* __restrict__ flag) {
    int b = blockIdx.x;
    if (b < 2048) {                       // weight fp32 [K][M] -> bf16 [M][K]
        int e = b * 256 + threadIdx.x;    // 0..524287
        const float* W; int base, K, M;
        if (e < 262144) {
            int r = e >> 16;
            W = (r == 0) ? Wq : (r == 1) ? Wk : (r == 2) ? Wv : Wo;
            base = r << 16; K = 256; M = 256;
        } else if (e < 393216) { W = Wm1; base = 262144; K = 256; M = 512; }
        else                   { W = Wm2; base = 393216; K = 512; M = 256; }
        int i = e - base;
        int m = i / K, k = i - m * K;
        wbf[e] = f2b(W[k * M + m]);
    } else if (b < 2560) {                // zero the 2MB bitmap
        bitmap[(size_t)(b - 2048) * 256 + threadIdx.x] = uint4{0, 0, 0, 0};
    } else if (threadIdx.x == 0) {        // edge dtype detect
        int is64 = 1;
        for (int i = 1; i < 128; i += 2)
            if (ei[i] != 0) { is64 = 0; break; }
        *flag = is64;
    }
}

// ---------------- build dedup'd adjacency bitmap --------------------------
__global__ __launch_bounds__(256) void build_adj(const int* __restrict__ ei, int E,
                                                 const int* __restrict__ flag,
                                                 unsigned* __restrict__ bitmap) {
    int e = blockIdx.x * blockDim.x + threadIdx.x;
    if (e >= E) return;
    int n, m;
    if (*flag) { n = ei[2 * e]; m = ei[2 * (E + e)]; }
    else       { n = ei[e];     m = ei[E + e]; }
    atomicOr(&bitmap[n * NWORDS + (m >> 5)], 1u << (m & 31));
}

// ---------------- LayerNorm: one block (256 thr) per row, bf16 out -------
__global__ __launch_bounds__(256) void ln_kernel(const float* __restrict__ x,
                                                 const float* __restrict__ g,
                                                 const float* __restrict__ b,
                                                 unsigned short* __restrict__ out) {
    int row = blockIdx.x, t = threadIdx.x;
    float v = x[row * D_MODEL + t];
    __shared__ float red[4];
    float s = v;
    #pragma unroll
    for (int off = 32; off; off >>= 1) s += __shfl_down(s, off, 64);
    if ((t & 63) == 0) red[t >> 6] = s;
    __syncthreads();
    float mu = (red[0] + red[1] + red[2] + red[3]) * (1.0f / 256.0f);
    __syncthreads();
    float d = v - mu;
    float s2 = d * d;
    #pragma unroll
    for (int off = 32; off; off >>= 1) s2 += __shfl_down(s2, off, 64);
    if ((t & 63) == 0) red[t >> 6] = s2;
    __syncthreads();
    float var = (red[0] + red[1] + red[2] + red[3]) * (1.0f / 256.0f);
    out[row * D_MODEL + t] = f2b(d * rsqrtf(var + 1e-5f) * g[t] + b[t]);
}

// ---------------- bf16 MFMA GEMM: 64x64 tile, 512 thr / 8 waves -----------
// Each wave: 16 rows x 32 cols (1x2 frags). BK=64, single-LDS-buffer
// pipeline: write LDS, sync, issue next K-step globals, MFMA, sync.
// MODE 1: +bias,GELU -> bf16 | 2: +bias+R -> f32 | 3: qkv 3-part bias -> bf16
template <int K, int MODE>
__global__ __launch_bounds__(512) void gemm_bf16(const unsigned short* __restrict__ A,
        const unsigned short* __restrict__ BT, const float* __restrict__ bias,
        const float* __restrict__ bias_k, const float* __restrict__ bias_v,
        const float* __restrict__ R, float* __restrict__ Cf,
        unsigned short* __restrict__ Cb, int M) {
    __shared__ unsigned short Asm[64][72];   // 9.2 KB, 2-way-free bank pattern
    __shared__ unsigned short Bsm[64][72];
    int tid = threadIdx.x;
    int brow = blockIdx.x * 64, bcol = blockIdx.y * 64;
    int wid = tid >> 6, lane = tid & 63;
    int wr = wid >> 1, wc = wid & 1;           // 4 row-waves x 2 col-waves
    int l15 = lane & 15, lhi = lane >> 4;
    int r0 = tid >> 3, c0 = (tid & 7) << 3;    // one short8 slot each for A,B
    const unsigned short* Ap = A + (size_t)(brow + r0) * K + c0;
    const unsigned short* Bp = BT + (size_t)(bcol + r0) * K + c0;

    f32x4 acc[2] = {};
    short8 areg = *(const short8*)(Ap);
    short8 breg = *(const short8*)(Bp);
    #pragma unroll
    for (int k0 = 0; k0 < K; k0 += 64) {
        *(short8*)&Asm[r0][c0] = areg;
        *(short8*)&Bsm[r0][c0] = breg;
        __syncthreads();
        if (k0 + 64 < K) {                      // issue next-tile loads early;
            areg = *(const short8*)(Ap + k0 + 64);   // latency hides under MFMA
            breg = *(const short8*)(Bp + k0 + 64);
        }
        #pragma unroll
        for (int ks = 0; ks < 2; ++ks) {
            int kc = ks * 32 + lhi * 8;
            short8 a_0 = *(const short8*)&Asm[wr * 16 + l15][kc];
            short8 b_0 = *(const short8*)&Bsm[wc * 32 + l15][kc];
            short8 b_1 = *(const short8*)&Bsm[wc * 32 + 16 + l15][kc];
            acc[0] = __builtin_amdgcn_mfma_f32_16x16x32_bf16(a_0, b_0, acc[0], 0, 0, 0);
            acc[1] = __builtin_amdgcn_mfma_f32_16x16x32_bf16(a_0, b_1, acc[1], 0, 0, 0);
        }
        __syncthreads();
    }
    #pragma unroll
    for (int sn = 0; sn < 2; ++sn) {
        int col = bcol + wc * 32 + sn * 16 + l15;
        float bs;
        if (MODE == 3)
            bs = (col < 256) ? bias[col]
               : (col < 512) ? bias_k[col - 256] : bias_v[col - 512];
        else
            bs = bias[col];
        #pragma unroll
        for (int r = 0; r < 4; ++r) {
            int row = brow + wr * 16 + lhi * 4 + r;
            float c = acc[sn][r] + bs;
            if (MODE == 1) {
                c = 0.5f * c * (1.0f + erff(c * 0.70710678118654752f));
                Cb[(size_t)row * M + col] = f2b(c);
            } else if (MODE == 2) {
                Cf[(size_t)row * M + col] = c + R[(size_t)row * M + col];
            } else {
                Cb[(size_t)row * M + col] = f2b(c);
            }
        }
    }
}

// ---------------- sparse attention w/ inline bitmap->index scan -----------
// qkv: [N][768] bf16 (q|k|v). 1 block/row, 8 head-groups of 32 lanes.
__global__ __launch_bounds__(256) void attn_kernel(const unsigned short* __restrict__ qkv,
        const unsigned* __restrict__ bitmap, unsigned short* __restrict__ y) {
    int n = blockIdx.x, tid = threadIdx.x;
    int h = tid >> 5, lane = tid & 31;
    __shared__ int sIdx[MAXC];
    __shared__ int wsum[2];
    __shared__ int scnt;

    // q load first: global latency hides under the bitmap scan
    const unsigned short* qp = qkv + (size_t)n * 768 + h * 32;
    float qreg[32];
    #pragma unroll
    for (int i = 0; i < 4; ++i) {
        short8 q8 = *(const short8*)(qp + i * 8);
        #pragma unroll
        for (int j = 0; j < 8; ++j) qreg[i * 8 + j] = b2f((unsigned short)q8[j]);
    }

    unsigned word = 0; int pc = 0, pre = 0;
    if (tid < 128) {                       // popc prefix scan of 128 words
        word = bitmap[n * NWORDS + tid];
        pc = __popc(word);
        pre = pc;
        #pragma unroll
        for (int off = 1; off < 64; off <<= 1) {
            int u = __shfl_up(pre, off, 64);
            if ((tid & 63) >= off) pre += u;
        }
        if ((tid & 63) == 63) wsum[tid >> 6] = pre;
    }
    __syncthreads();
    if (tid < 128) {
        int base = (tid >= 64) ? wsum[0] : 0;
        int off = base + pre - pc;
        while (word) {
            int bit = __ffs(word) - 1;
            word &= word - 1;
            if (off < MAXC) sIdx[off] = (tid << 5) + bit;
            ++off;
        }
        if (tid == 127) scnt = min(base + pre, MAXC);
    }
    __syncthreads();
    int c = scnt;

    const float sc = 0.17677669529663687f;   // 1/sqrt(32)
    float m_run = -INFINITY, S = 0.0f, acc = 0.0f;
    for (int b0 = 0; b0 < c; b0 += 32) {
        int j = b0 + lane;
        float s = -INFINITY;
        if (j < c) {
            const unsigned short* kp = qkv + (size_t)sIdx[j] * 768 + 256 + h * 32;
            float d = 0.0f;
            #pragma unroll
            for (int i = 0; i < 4; ++i) {
                short8 k8 = *(const short8*)(kp + i * 8);
                #pragma unroll
                for (int e = 0; e < 8; ++e)
                    d = fmaf(qreg[i * 8 + e], b2f((unsigned short)k8[e]), d);
            }
            s = d * sc;
        }
        float bm = s;
        #pragma unroll
        for (int off = 16; off; off >>= 1) bm = fmaxf(bm, __shfl_xor(bm, off, 32));
        float newM = fmaxf(m_run, bm);
        float p = (j < c) ? __expf(s - newM) : 0.0f;
        float bs = p;
        #pragma unroll
        for (int off = 16; off; off >>= 1) bs += __shfl_xor(bs, off, 32);
        float scale = __expf(m_run - newM);
        S = S * scale + bs;
        acc *= scale;
        int lim = min(32, c - b0);
        const unsigned short* vbase = qkv + 512 + h * 32 + lane;
        #pragma unroll 4
        for (int jj = 0; jj < lim; ++jj) {
            float pj = __shfl(p, jj, 32);
            int m = sIdx[b0 + jj];
            acc = fmaf(pj, b2f(vbase[(size_t)m * 768]), acc);
        }
        m_run = newM;
    }
    y[(size_t)n * 256 + h * 32 + lane] = f2b(acc / S);
}

extern "C" void kernel_launch(void* const* d_in, const int* in_sizes, int n_in,
                              void* d_out, int out_size, void* d_ws, size_t ws_size,
                              hipStream_t stream) {
    const float* x   = (const float*)d_in[0];
    const int*   ei  = (const int*)d_in[1];
    const float* Wq  = (const float*)d_in[2];  const float* bq  = (const float*)d_in[3];
    const float* Wk  = (const float*)d_in[4];  const float* bk  = (const float*)d_in[5];
    const float* Wv  = (const float*)d_in[6];  const float* bv  = (const float*)d_in[7];
    const float* Wo  = (const float*)d_in[8];  const float* bo  = (const float*)d_in[9];
    const float* g1  = (const float*)d_in[10]; const float* b1  = (const float*)d_in[11];
    const float* g2  = (const float*)d_in[12]; const float* b2  = (const float*)d_in[13];
    const float* Wm1 = (const float*)d_in[14]; const float* bm1 = (const float*)d_in[15];
    const float* Wm2 = (const float*)d_in[16]; const float* bm2 = (const float*)d_in[17];
    float* out = (float*)d_out;
    int E = in_sizes[1] / 2;   // 135168

    char* WS = (char*)d_ws;
    const size_t MB = 1u << 20;
    unsigned*       bitmap = (unsigned*)WS;                     // [0,2MB)
    int*            flag   = (int*)(WS + 2 * MB);               // 4B
    unsigned short* wbf    = (unsigned short*)(WS + 3 * MB);    // 1MB
    unsigned short* y      = (unsigned short*)(WS + 4 * MB);    // 2MB
    float*          x1     = (float*)(WS + 6 * MB);             // 4MB
    unsigned short* m1     = (unsigned short*)(WS + 10 * MB);   // 4MB
    unsigned short* h      = (unsigned short*)(WS + 14 * MB);   // 2MB (h, then h2)
    unsigned short* qkv    = (unsigned short*)(WS + 16 * MB);   // 6MB

    const unsigned short* WTqkv = wbf;            // q|k|v stacked along M
    const unsigned short* WTo   = wbf + 196608;
    const unsigned short* WTm1  = wbf + 262144;
    const unsigned short* WTm2  = wbf + 393216;

    prep_kernel<<<2561, 256, 0, stream>>>(Wq, Wk, Wv, Wo, Wm1, Wm2, wbf,
                                          (uint4*)bitmap, ei, flag);
    ln_kernel<<<N_NODES, 256, 0, stream>>>(x, g1, b1, h);
    build_adj<<<(E + 255) / 256, 256, 0, stream>>>(ei, E, flag, bitmap);

    dim3 gqkv(64, 12), g256(64, 4), g512(64, 8);
    gemm_bf16<256, 3><<<gqkv, 512, 0, stream>>>(h, WTqkv, bq, bk, bv,
                                                nullptr, nullptr, qkv, 768);

    attn_kernel<<<N_NODES, 256, 0, stream>>>(qkv, bitmap, y);

    // x1 = x + y @ Wo + bo
    gemm_bf16<256, 2><<<g256, 512, 0, stream>>>(y, WTo, bo, nullptr, nullptr,
                                                x, x1, nullptr, 256);
    ln_kernel<<<N_NODES, 256, 0, stream>>>(x1, g2, b2, h);
    // m1 = gelu(LN2(x1) @ Wm1 + bm1)
    gemm_bf16<256, 1><<<g512, 512, 0, stream>>>(h, WTm1, bm1, nullptr, nullptr,
                                                nullptr, nullptr, m1, 512);
    // out = x1 + m1 @ Wm2 + bm2
    gemm_bf16<512, 2><<<g256, 512, 0, stream>>>(m1, WTm2, bm2, nullptr, nullptr,
                                                x1, out, nullptr, 256);
}

// Round 8
// 82.702 us; speedup vs baseline: 1.1783x; 1.0736x over previous
//
#include <hip/hip_runtime.h>
#include <hip/hip_bf16.h>

#define N_NODES 4096
#define D_MODEL 256
#define NWORDS 128   // bitmap words per row (4096/32)
#define MAXC 512     // max neighbors per row (avg ~33)

typedef __attribute__((ext_vector_type(8))) short short8;
typedef __attribute__((ext_vector_type(4))) float f32x4;

__device__ __forceinline__ unsigned short f2b(float f) {  // fp32 -> bf16 RTN
    unsigned u = __float_as_uint(f);
    return (unsigned short)((u + 0x7FFFu + ((u >> 16) & 1u)) >> 16);
}
__device__ __forceinline__ float b2f(unsigned short u) {
    return __uint_as_float((unsigned)u << 16);
}

// ---- prep: convw (0..2047) | zero bitmap (2048..2559) | detect (2560)
// ----       | LN1 rows (2561..6656) ---------------------------------------
__global__ __launch_bounds__(256) void prep_kernel(const float* __restrict__ Wq,
        const float* __restrict__ Wk, const float* __restrict__ Wv,
        const float* __restrict__ Wo, const float* __restrict__ Wm1,
        const float* __restrict__ Wm2, unsigned short* __restrict__ wbf,
        uint4* __restrict__ bitmap, const int* __restrict__ ei,
        int* __restrict__ flag, const float* __restrict__ x,
        const float* __restrict__ g1, const float* __restrict__ b1,
        unsigned short* __restrict__ h) {
    int b = blockIdx.x, t = threadIdx.x;
    if (b < 2048) {                       // weight fp32 [K][M] -> bf16 [M][K]
        int e = b * 256 + t;              // 0..524287
        const float* W; int base, K, M;
        if (e < 262144) {
            int r = e >> 16;
            W = (r == 0) ? Wq : (r == 1) ? Wk : (r == 2) ? Wv : Wo;
            base = r << 16; K = 256; M = 256;
        } else if (e < 393216) { W = Wm1; base = 262144; K = 256; M = 512; }
        else                   { W = Wm2; base = 393216; K = 512; M = 256; }
        int i = e - base;
        int m = i / K, k = i - m * K;
        wbf[e] = f2b(W[k * M + m]);
    } else if (b < 2560) {                // zero the 2MB bitmap
        bitmap[(size_t)(b - 2048) * 256 + t] = uint4{0, 0, 0, 0};
    } else if (b == 2560) {               // edge dtype detect
        if (t == 0) {
            int is64 = 1;
            for (int i = 1; i < 128; i += 2)
                if (ei[i] != 0) { is64 = 0; break; }
            *flag = is64;
        }
    } else {                              // LayerNorm1: one row per block
        int row = b - 2561;
        float v = x[row * D_MODEL + t];
        __shared__ float red[4];
        float s = v;
        #pragma unroll
        for (int off = 32; off; off >>= 1) s += __shfl_down(s, off, 64);
        if ((t & 63) == 0) red[t >> 6] = s;
        __syncthreads();
        float mu = (red[0] + red[1] + red[2] + red[3]) * (1.0f / 256.0f);
        __syncthreads();
        float d = v - mu;
        float s2 = d * d;
        #pragma unroll
        for (int off = 32; off; off >>= 1) s2 += __shfl_down(s2, off, 64);
        if ((t & 63) == 0) red[t >> 6] = s2;
        __syncthreads();
        float var = (red[0] + red[1] + red[2] + red[3]) * (1.0f / 256.0f);
        h[row * D_MODEL + t] = f2b(d * rsqrtf(var + 1e-5f) * g1[t] + b1[t]);
    }
}

// ---- bf16 MFMA GEMM: 64x64 tile, 512 thr / 8 waves, BK=64 ----------------
// MODE 1: +bias,GELU -> bf16 | 2: +bias+R -> f32 | 3: qkv 3-part bias -> bf16
//   (MODE 3 additionally runs build_adj in blocks [0,nadj) )
// LNA:   A is f32 + per-row partial stats -> layernorm during A-staging
// STATS: epilogue emits per-row partial sum/sumsq of C (for downstream LN)
template <int K, int MODE, bool LNA, bool STATS>
__global__ __launch_bounds__(512) void gemm_bf16(const unsigned short* __restrict__ A,
        const float* __restrict__ Af, const float* __restrict__ psum,
        const float* __restrict__ psum2, const float* __restrict__ lng,
        const float* __restrict__ lnb, const unsigned short* __restrict__ BT,
        const float* __restrict__ bias, const float* __restrict__ bias_k,
        const float* __restrict__ bias_v, const float* __restrict__ R,
        float* __restrict__ Cf, unsigned short* __restrict__ Cb,
        float* __restrict__ opsum, float* __restrict__ opsum2, int M,
        const int* __restrict__ ei, int E, const int* __restrict__ flag,
        unsigned* __restrict__ bitmap, int nadj) {
    int tid = threadIdx.x;
    if (MODE == 3 && (int)blockIdx.x < nadj) {   // fused edge scatter
        int e = (int)blockIdx.x * 512 + tid;
        if (e < E) {
            int n, m;
            if (*flag) { n = ei[2 * e]; m = ei[2 * (E + e)]; }
            else       { n = ei[e];     m = ei[E + e]; }
            atomicOr(&bitmap[n * NWORDS + (m >> 5)], 1u << (m & 31));
        }
        return;
    }
    __shared__ unsigned short Asm[64][72];
    __shared__ unsigned short Bsm[64][72];
    __shared__ float psA[64][2], psA2[64][2];
    __shared__ float muS[64], invS[64];

    int bx2  = (MODE == 3) ? ((int)blockIdx.x - nadj) : 0;
    int brow = (MODE == 3) ? ((bx2 & 63) << 6) : ((int)blockIdx.x << 6);
    int by   = (MODE == 3) ? (bx2 >> 6) : (int)blockIdx.y;
    int bcol = by << 6;
    int wid = tid >> 6, lane = tid & 63;
    int wr = wid >> 1, wc = wid & 1;             // 4 row-waves x 2 col-waves
    int l15 = lane & 15, lhi = lane >> 4;
    int r0 = tid >> 3, c0 = (tid & 7) << 3;

    float mu_r = 0.f, inv_r = 0.f;
    if (LNA) {   // combine partial stats once per block
        if (tid < 64) {
            float4 s4 = ((const float4*)psum)[brow + tid];
            float4 q4 = ((const float4*)psum2)[brow + tid];
            float S  = s4.x + s4.y + s4.z + s4.w;
            float S2 = q4.x + q4.y + q4.z + q4.w;
            float mu = S * (1.0f / 256.0f);
            muS[tid] = mu;
            invS[tid] = rsqrtf(S2 * (1.0f / 256.0f) - mu * mu + 1e-5f);
        }
        __syncthreads();
        mu_r = muS[r0]; inv_r = invS[r0];
    }

    const unsigned short* Bp = BT + (size_t)(bcol + r0) * K + c0;
    f32x4 acc[2] = {};
    short8 areg;
    float4 xa, xb, ga, gb, ba, bb;
    if (LNA) {
        const float* Xp = Af + (size_t)(brow + r0) * 256 + c0;
        xa = *(const float4*)(Xp);
        xb = *(const float4*)(Xp + 4);
        ga = *(const float4*)(lng + c0); gb = *(const float4*)(lng + c0 + 4);
        ba = *(const float4*)(lnb + c0); bb = *(const float4*)(lnb + c0 + 4);
    } else {
        areg = *(const short8*)(A + (size_t)(brow + r0) * K + c0);
    }
    short8 breg = *(const short8*)(Bp);

    #pragma unroll
    for (int k0 = 0; k0 < K; k0 += 64) {
        if (LNA) {   // layernorm on the fly into LDS
            float xv[8] = {xa.x, xa.y, xa.z, xa.w, xb.x, xb.y, xb.z, xb.w};
            float gv[8] = {ga.x, ga.y, ga.z, ga.w, gb.x, gb.y, gb.z, gb.w};
            float bv[8] = {ba.x, ba.y, ba.z, ba.w, bb.x, bb.y, bb.z, bb.w};
            short8 o;
            #pragma unroll
            for (int j = 0; j < 8; ++j)
                o[j] = (short)f2b((xv[j] - mu_r) * inv_r * gv[j] + bv[j]);
            *(short8*)&Asm[r0][c0] = o;
        } else {
            *(short8*)&Asm[r0][c0] = areg;
        }
        *(short8*)&Bsm[r0][c0] = breg;
        __syncthreads();
        if (k0 + 64 < K) {                      // prefetch next K-step
            if (LNA) {
                const float* Xp = Af + (size_t)(brow + r0) * 256 + k0 + 64 + c0;
                xa = *(const float4*)(Xp);
                xb = *(const float4*)(Xp + 4);
                ga = *(const float4*)(lng + k0 + 64 + c0);
                gb = *(const float4*)(lng + k0 + 64 + c0 + 4);
                ba = *(const float4*)(lnb + k0 + 64 + c0);
                bb = *(const float4*)(lnb + k0 + 64 + c0 + 4);
            } else {
                areg = *(const short8*)(A + (size_t)(brow + r0) * K + k0 + 64 + c0);
            }
            breg = *(const short8*)(Bp + k0 + 64);
        }
        #pragma unroll
        for (int ks = 0; ks < 2; ++ks) {
            int kc = ks * 32 + lhi * 8;
            short8 a_0 = *(const short8*)&Asm[wr * 16 + l15][kc];
            short8 b_0 = *(const short8*)&Bsm[wc * 32 + l15][kc];
            short8 b_1 = *(const short8*)&Bsm[wc * 32 + 16 + l15][kc];
            acc[0] = __builtin_amdgcn_mfma_f32_16x16x32_bf16(a_0, b_0, acc[0], 0, 0, 0);
            acc[1] = __builtin_amdgcn_mfma_f32_16x16x32_bf16(a_0, b_1, acc[1], 0, 0, 0);
        }
        __syncthreads();
    }

    float cs[2][4];
    #pragma unroll
    for (int sn = 0; sn < 2; ++sn) {
        int col = bcol + wc * 32 + sn * 16 + l15;
        float bs;
        if (MODE == 3)
            bs = (col < 256) ? bias[col]
               : (col < 512) ? bias_k[col - 256] : bias_v[col - 512];
        else
            bs = bias[col];
        #pragma unroll
        for (int r = 0; r < 4; ++r) {
            int row = brow + wr * 16 + lhi * 4 + r;
            float c = acc[sn][r] + bs;
            if (MODE == 1) {
                c = 0.5f * c * (1.0f + erff(c * 0.70710678118654752f));
                Cb[(size_t)row * M + col] = f2b(c);
            } else if (MODE == 2) {
                c += R[(size_t)row * M + col];
                Cf[(size_t)row * M + col] = c;
            } else {
                Cb[(size_t)row * M + col] = f2b(c);
            }
            if (STATS) cs[sn][r] = c;
        }
    }
    if (STATS) {   // deterministic per-row partial stats over this 64-col strip
        #pragma unroll
        for (int r = 0; r < 4; ++r) {
            float s  = cs[0][r] + cs[1][r];
            float s2 = cs[0][r] * cs[0][r] + cs[1][r] * cs[1][r];
            #pragma unroll
            for (int off = 1; off < 16; off <<= 1) {
                s  += __shfl_xor(s, off, 64);
                s2 += __shfl_xor(s2, off, 64);
            }
            if (l15 == 0) {
                int rl = wr * 16 + lhi * 4 + r;
                psA[rl][wc] = s; psA2[rl][wc] = s2;
            }
        }
        __syncthreads();
        if (tid < 64) {
            opsum [(size_t)(brow + tid) * 4 + by] = psA[tid][0] + psA[tid][1];
            opsum2[(size_t)(brow + tid) * 4 + by] = psA2[tid][0] + psA2[tid][1];
        }
    }
}

// ---------------- sparse attention w/ inline bitmap->index scan -----------
// qkv: [N][768] bf16 (q|k|v). 1 block/row, 8 head-groups of 32 lanes.
__global__ __launch_bounds__(256) void attn_kernel(const unsigned short* __restrict__ qkv,
        const unsigned* __restrict__ bitmap, unsigned short* __restrict__ y) {
    int n = blockIdx.x, tid = threadIdx.x;
    int h = tid >> 5, lane = tid & 31;
    __shared__ int sIdx[MAXC];
    __shared__ int wsum[2];
    __shared__ int scnt;

    // q load first: global latency hides under the bitmap scan
    const unsigned short* qp = qkv + (size_t)n * 768 + h * 32;
    float qreg[32];
    #pragma unroll
    for (int i = 0; i < 4; ++i) {
        short8 q8 = *(const short8*)(qp + i * 8);
        #pragma unroll
        for (int j = 0; j < 8; ++j) qreg[i * 8 + j] = b2f((unsigned short)q8[j]);
    }

    unsigned word = 0; int pc = 0, pre = 0;
    if (tid < 128) {                       // popc prefix scan of 128 words
        word = bitmap[n * NWORDS + tid];
        pc = __popc(word);
        pre = pc;
        #pragma unroll
        for (int off = 1; off < 64; off <<= 1) {
            int u = __shfl_up(pre, off, 64);
            if ((tid & 63) >= off) pre += u;
        }
        if ((tid & 63) == 63) wsum[tid >> 6] = pre;
    }
    __syncthreads();
    if (tid < 128) {
        int base = (tid >= 64) ? wsum[0] : 0;
        int off = base + pre - pc;
        while (word) {
            int bit = __ffs(word) - 1;
            word &= word - 1;
            if (off < MAXC) sIdx[off] = (tid << 5) + bit;
            ++off;
        }
        if (tid == 127) scnt = min(base + pre, MAXC);
    }
    __syncthreads();
    int c = scnt;

    const float sc = 0.17677669529663687f;   // 1/sqrt(32)
    float m_run = -INFINITY, S = 0.0f, acc = 0.0f;
    for (int b0 = 0; b0 < c; b0 += 32) {
        int j = b0 + lane;
        float s = -INFINITY;
        if (j < c) {
            const unsigned short* kp = qkv + (size_t)sIdx[j] * 768 + 256 + h * 32;
            float d = 0.0f;
            #pragma unroll
            for (int i = 0; i < 4; ++i) {
                short8 k8 = *(const short8*)(kp + i * 8);
                #pragma unroll
                for (int e = 0; e < 8; ++e)
                    d = fmaf(qreg[i * 8 + e], b2f((unsigned short)k8[e]), d);
            }
            s = d * sc;
        }
        float bm = s;
        #pragma unroll
        for (int off = 16; off; off >>= 1) bm = fmaxf(bm, __shfl_xor(bm, off, 32));
        float newM = fmaxf(m_run, bm);
        float p = (j < c) ? __expf(s - newM) : 0.0f;
        float bs = p;
        #pragma unroll
        for (int off = 16; off; off >>= 1) bs += __shfl_xor(bs, off, 32);
        float scale = __expf(m_run - newM);
        S = S * scale + bs;
        acc *= scale;
        int lim = min(32, c - b0);
        const unsigned short* vbase = qkv + 512 + h * 32 + lane;
        #pragma unroll 4
        for (int jj = 0; jj < lim; ++jj) {
            float pj = __shfl(p, jj, 32);
            int m = sIdx[b0 + jj];
            acc = fmaf(pj, b2f(vbase[(size_t)m * 768]), acc);
        }
        m_run = newM;
    }
    y[(size_t)n * 256 + h * 32 + lane] = f2b(acc / S);
}

extern "C" void kernel_launch(void* const* d_in, const int* in_sizes, int n_in,
                              void* d_out, int out_size, void* d_ws, size_t ws_size,
                              hipStream_t stream) {
    const float* x   = (const float*)d_in[0];
    const int*   ei  = (const int*)d_in[1];
    const float* Wq  = (const float*)d_in[2];  const float* bq  = (const float*)d_in[3];
    const float* Wk  = (const float*)d_in[4];  const float* bk  = (const float*)d_in[5];
    const float* Wv  = (const float*)d_in[6];  const float* bv  = (const float*)d_in[7];
    const float* Wo  = (const float*)d_in[8];  const float* bo  = (const float*)d_in[9];
    const float* g1  = (const float*)d_in[10]; const float* b1  = (const float*)d_in[11];
    const float* g2  = (const float*)d_in[12]; const float* b2  = (const float*)d_in[13];
    const float* Wm1 = (const float*)d_in[14]; const float* bm1 = (const float*)d_in[15];
    const float* Wm2 = (const float*)d_in[16]; const float* bm2 = (const float*)d_in[17];
    float* out = (float*)d_out;
    int E = in_sizes[1] / 2;   // 135168
    int nadj = (E + 511) / 512;

    char* WS = (char*)d_ws;
    const size_t MB = 1u << 20;
    unsigned*       bitmap = (unsigned*)WS;                        // [0,2MB)
    int*            flag   = (int*)(WS + 2 * MB);                  // 4B
    float*          psum   = (float*)(WS + 2 * MB + 4096);         // 64KB [N][4]
    float*          psum2  = (float*)(WS + 2 * MB + 4096 + 65536); // 64KB
    unsigned short* wbf    = (unsigned short*)(WS + 3 * MB);       // 1MB
    unsigned short* y      = (unsigned short*)(WS + 4 * MB);       // 2MB
    float*          x1     = (float*)(WS + 6 * MB);                // 4MB
    unsigned short* m1     = (unsigned short*)(WS + 10 * MB);      // 4MB
    unsigned short* h      = (unsigned short*)(WS + 14 * MB);      // 2MB
    unsigned short* qkv    = (unsigned short*)(WS + 16 * MB);      // 6MB

    const unsigned short* WTqkv = wbf;            // q|k|v stacked along M
    const unsigned short* WTo   = wbf + 196608;
    const unsigned short* WTm1  = wbf + 262144;
    const unsigned short* WTm2  = wbf + 393216;

    // 1) convw + zero bitmap + detect + LN1
    prep_kernel<<<6657, 256, 0, stream>>>(Wq, Wk, Wv, Wo, Wm1, Wm2, wbf,
                                          (uint4*)bitmap, ei, flag, x, g1, b1, h);
    // 2) build_adj (blocks [0,nadj)) + qkv = h @ Wqkv + b (blocks [nadj, nadj+768))
    gemm_bf16<256, 3, false, false><<<nadj + 768, 512, 0, stream>>>(h, nullptr,
            nullptr, nullptr, nullptr, nullptr, WTqkv, bq, bk, bv, nullptr,
            nullptr, qkv, nullptr, nullptr, 768, ei, E, flag, bitmap, nadj);
    // 3) attention
    attn_kernel<<<N_NODES, 256, 0, stream>>>(qkv, bitmap, y);
    // 4) x1 = x + y @ Wo + bo   (+ per-row partial LN2 stats)
    gemm_bf16<256, 2, false, true><<<dim3(64, 4), 512, 0, stream>>>(y, nullptr,
            nullptr, nullptr, nullptr, nullptr, WTo, bo, nullptr, nullptr, x,
            x1, nullptr, psum, psum2, 256, nullptr, 0, nullptr, nullptr, 0);
    // 5) m1 = gelu(LN2(x1) @ Wm1 + bm1)   (LN2 applied during A-staging)
    gemm_bf16<256, 1, true, false><<<dim3(64, 8), 512, 0, stream>>>(nullptr, x1,
            psum, psum2, g2, b2, WTm1, bm1, nullptr, nullptr, nullptr,
            nullptr, m1, nullptr, nullptr, 512, nullptr, 0, nullptr, nullptr, 0);
    // 6) out = x1 + m1 @ Wm2 + bm2
    gemm_bf16<512, 2, false, false><<<dim3(64, 4), 512, 0, stream>>>(m1, nullptr,
            nullptr, nullptr, nullptr, nullptr, WTm2, bm2, nullptr, nullptr, x1,
            out, nullptr, nullptr, nullptr, 256, nullptr, 0, nullptr, nullptr, 0);
}